// Round 4
// baseline (1829.348 us; speedup 1.0000x reference)
//
#include <hip/hip_runtime.h>
#include <cstddef>
#include <cstdint>

#define BSZ 512
#define SEQ 100

typedef __bf16 bf16_t;
typedef __attribute__((ext_vector_type(8))) __bf16 bf16x8;
typedef __attribute__((ext_vector_type(4))) float f32x4;
typedef __attribute__((ext_vector_type(2))) float f32x2;
typedef unsigned short ushort_t;

__device__ __forceinline__ float sigmoidf_(float v){ return 1.f/(1.f + __expf(-v)); }
__device__ __forceinline__ float siluf_(float v){ return v * sigmoidf_(v); }
__device__ __forceinline__ float softplusf_(float v){ return (v > 20.f) ? v : __logf(1.f + __expf(v)); }

// ---------------------------------------------------------------------------
__global__ __launch_bounds__(256) void cvt_bf16_kernel(
    const float* __restrict__ src, bf16_t* __restrict__ dst, int n)
{
    int i = blockIdx.x*256 + threadIdx.x;
    if (i < n) dst[i] = (bf16_t)src[i];
}

__global__ __launch_bounds__(256) void prep_outw_kernel(
    const float* __restrict__ of, const float* __restrict__ ob, bf16_t* __restrict__ W)
{
    int i = blockIdx.x*256 + threadIdx.x;
    if (i < 512*2048){
        int o = i >> 11, k = i & 2047;
        W[i] = (bf16_t)((k < 1024) ? of[o*1024 + k] : ob[o*1024 + (k - 1024)]);
    }
}

__global__ __launch_bounds__(256) void prep_convw_kernel(
    const float* __restrict__ c1w, const float* __restrict__ c2w,
    bf16_t* __restrict__ W1p, bf16_t* __restrict__ W2p)
{
    int i = blockIdx.x*256 + threadIdx.x;
    if (i < 128*96){
        int o = i / 96, kk = i - o*96, k = kk >> 5, c = kk & 31;
        W1p[i] = (c < 22) ? (bf16_t)c1w[(o*22 + c)*3 + k] : (bf16_t)0.f;
    }
    if (i < 256*384){
        int o = i / 384, kk = i - o*384, k = kk >> 7, c = kk & 127;
        W2p[i] = (bf16_t)c2w[(o*128 + c)*3 + k];
    }
}

// ---------------------------------------------------------------------------
// FE0: id-embed (2 LN) -> comb[...,0:256]; build F0pad; zero F1pad boundary.
// ---------------------------------------------------------------------------
__global__ __launch_bounds__(256) void fe0_kernel(
    const float* __restrict__ x,
    const float* __restrict__ fe_w, const float* __restrict__ fe_b,
    const float* __restrict__ g1, const float* __restrict__ b1,
    const float* __restrict__ g2, const float* __restrict__ b2,
    bf16_t* __restrict__ comb, bf16_t* __restrict__ F0pad, bf16_t* __restrict__ F1pad)
{
    const int b = blockIdx.x;
    const int t = threadIdx.x;
    const int wv = t >> 6, lane = t & 63;

    float few[4], feb[4], lg1[4], lb1[4], lg2[4], lb2[4];
    #pragma unroll
    for (int q = 0; q < 4; ++q){
        int j = lane + 64*q;
        few[q] = fe_w[j]; feb[q] = fe_b[j];
        lg1[q] = g1[j];  lb1[q] = b1[j];
        lg2[q] = g2[j];  lb2[q] = b2[j];
    }
    for (int l = wv; l < SEQ; l += 4){
        float m = fabsf(x[(size_t)(b*SEQ + l)*23]);
        float e[4];
        float s1 = 0.f, s2 = 0.f;
        #pragma unroll
        for (int q = 0; q < 4; ++q){ e[q] = m*few[q] + feb[q]; s1 += e[q]; s2 += e[q]*e[q]; }
        #pragma unroll
        for (int off = 32; off > 0; off >>= 1){ s1 += __shfl_xor(s1, off); s2 += __shfl_xor(s2, off); }
        float mean = s1 * (1.f/256.f);
        float rstd = rsqrtf(s2*(1.f/256.f) - mean*mean + 1e-5f);
        s1 = 0.f; s2 = 0.f;
        #pragma unroll
        for (int q = 0; q < 4; ++q){
            e[q] = fmaxf((e[q]-mean)*rstd*lg1[q] + lb1[q], 0.f);
            s1 += e[q]; s2 += e[q]*e[q];
        }
        #pragma unroll
        for (int off = 32; off > 0; off >>= 1){ s1 += __shfl_xor(s1, off); s2 += __shfl_xor(s2, off); }
        mean = s1 * (1.f/256.f);
        rstd = rsqrtf(s2*(1.f/256.f) - mean*mean + 1e-5f);
        #pragma unroll
        for (int q = 0; q < 4; ++q){
            float v = fmaxf((e[q]-mean)*rstd*lg2[q] + lb2[q], 0.f);
            comb[(size_t)(b*SEQ + l)*512 + lane + 64*q] = (bf16_t)v;
        }
    }

    for (int idx = t; idx < 102*32; idx += 256){
        int r = idx >> 5, c = idx & 31;
        float v = 0.f;
        if (r >= 1 && r <= SEQ && c < 22) v = x[(size_t)(b*SEQ + r - 1)*23 + 1 + c];
        F0pad[(size_t)(b*102 + r)*32 + c] = (bf16_t)v;
    }
    if (t < 128) F1pad[(size_t)(b*102 + 0)*128 + t] = (bf16_t)0.f;
    else F1pad[(size_t)(b*102 + 101)*128 + (t - 128)] = (bf16_t)0.f;
}

// ---------------------------------------------------------------------------
// Conv-as-GEMM (z-batched): C[m,n] = relu(sum_k A_z[m*lda + k]*W[n,k] + bias[n])
// ---------------------------------------------------------------------------
__global__ __launch_bounds__(256) void gemm_conv_kernel(
    const bf16_t* __restrict__ Abase, int lda, int Az,
    const bf16_t* __restrict__ W, int K, int N,
    const float* __restrict__ bias,
    bf16_t* __restrict__ Cbase, int ldc, int Cb, int coff, int noff, int Mtot)
{
    __shared__ bf16_t As[128*32];
    __shared__ bf16_t Ws[128*32];
    const bf16_t* A = Abase + (size_t)blockIdx.z * Az;
    const int t = threadIdx.x;
    const int lane = t & 63, w = t >> 6;
    const int n0 = blockIdx.y * 128;
    const int rsub = lane >> 2, csub = lane & 3;
    const int col = lane & 15, quad = lane >> 4;
    const int wOffM = (w & 1) * 64, wOffN = (w >> 1) * 64;

    f32x4 acc[4][4];
    #pragma unroll
    for (int i = 0; i < 4; ++i)
        #pragma unroll
        for (int j = 0; j < 4; ++j)
            acc[i][j] = (f32x4){0.f, 0.f, 0.f, 0.f};

    for (int k0 = 0; k0 < K; k0 += 32){
        __syncthreads();
        #pragma unroll
        for (int q = 0; q < 2; ++q){
            const int rt = w*32 + q*16 + rsub;
            const int lq = csub ^ ((rt >> 1) & 3);
            int ra = (rt < Mtot) ? rt : (Mtot - 1);
            const bf16_t* ga = A + (size_t)ra*lda + k0 + lq*8;
            __builtin_amdgcn_global_load_lds(
                (const __attribute__((address_space(1))) void*)ga,
                (__attribute__((address_space(3))) void*)&As[(w*32 + q*16)*32], 16, 0, 0);
            const bf16_t* gw = W + (size_t)(n0 + rt)*K + k0 + lq*8;
            __builtin_amdgcn_global_load_lds(
                (const __attribute__((address_space(1))) void*)gw,
                (__attribute__((address_space(3))) void*)&Ws[(w*32 + q*16)*32], 16, 0, 0);
        }
        __syncthreads();

        bf16x8 af[4], bfv[4];
        #pragma unroll
        for (int i = 0; i < 4; ++i){
            const int ra = wOffM + i*16 + col;
            af[i]  = *(const bf16x8*)&As[ra*32 + (quad ^ ((ra >> 1) & 3))*8];
            const int rb = wOffN + i*16 + col;
            bfv[i] = *(const bf16x8*)&Ws[rb*32 + (quad ^ ((rb >> 1) & 3))*8];
        }
        #pragma unroll
        for (int i = 0; i < 4; ++i)
            #pragma unroll
            for (int j = 0; j < 4; ++j)
                acc[i][j] = __builtin_amdgcn_mfma_f32_16x16x32_bf16(af[i], bfv[j], acc[i][j], 0, 0, 0);
    }

    #pragma unroll
    for (int i = 0; i < 4; ++i){
        const int gmb = wOffM + i*16 + quad*4;
        #pragma unroll
        for (int j = 0; j < 4; ++j){
            const int gn = n0 + wOffN + j*16 + col;
            const float bb = bias[gn];
            #pragma unroll
            for (int r = 0; r < 4; ++r){
                const int gm = gmb + r;
                if (gm < Mtot){
                    float v = fmaxf(acc[i][j][r] + bb, 0.f);
                    Cbase[((size_t)blockIdx.z*Cb + coff + gm)*ldc + noff + gn] = (bf16_t)v;
                }
            }
        }
    }
}

// ---------------------------------------------------------------------------
// Merged in-proj GEMM: A=comb (M,512), W=[mf_in; mb_in] (4096,512).
// ---------------------------------------------------------------------------
__global__ __launch_bounds__(256) void gemm_in_kernel(
    const bf16_t* __restrict__ A, int lda, int Mtot,
    const bf16_t* __restrict__ W, int K,
    bf16_t* __restrict__ xy, bf16_t* __restrict__ z)
{
    __shared__ bf16_t smem[128*132];          // 33,792 B; staging uses first 32 KB
    bf16_t* As0 = smem;
    bf16_t* As1 = smem + 4096;
    bf16_t* Ws0 = smem + 8192;
    bf16_t* Ws1 = smem + 12288;
    const int t = threadIdx.x;
    const int lane = t & 63, w = t >> 6;
    const int m0 = blockIdx.x * 128, n0 = blockIdx.y * 128;
    const int rsub = lane >> 2, csub = lane & 3;
    const int col = lane & 15, quad = lane >> 4;
    const int wOffM = (w & 1) * 64, wOffN = (w >> 1) * 64;

    f32x4 acc[4][4];
    #pragma unroll
    for (int i = 0; i < 4; ++i)
        #pragma unroll
        for (int j = 0; j < 4; ++j)
            acc[i][j] = (f32x4){0.f, 0.f, 0.f, 0.f};

    for (int k0 = 0; k0 < K; k0 += 64){
        __syncthreads();
        #pragma unroll
        for (int hh = 0; hh < 2; ++hh){
            bf16_t* Asb = hh ? As1 : As0;
            bf16_t* Wsb = hh ? Ws1 : Ws0;
            #pragma unroll
            for (int q = 0; q < 2; ++q){
                const int rt = w*32 + q*16 + rsub;
                const int lq = csub ^ ((rt >> 1) & 3);
                int ra = m0 + rt; ra = (ra < Mtot) ? ra : (Mtot - 1);
                const bf16_t* ga = A + (size_t)ra*lda + k0 + hh*32 + lq*8;
                __builtin_amdgcn_global_load_lds(
                    (const __attribute__((address_space(1))) void*)ga,
                    (__attribute__((address_space(3))) void*)&Asb[(w*32 + q*16)*32], 16, 0, 0);
                const bf16_t* gw = W + (size_t)(n0 + rt)*K + k0 + hh*32 + lq*8;
                __builtin_amdgcn_global_load_lds(
                    (const __attribute__((address_space(1))) void*)gw,
                    (__attribute__((address_space(3))) void*)&Wsb[(w*32 + q*16)*32], 16, 0, 0);
            }
        }
        __syncthreads();

        #pragma unroll
        for (int hh = 0; hh < 2; ++hh){
            bf16_t* Asb = hh ? As1 : As0;
            bf16_t* Wsb = hh ? Ws1 : Ws0;
            bf16x8 af[4], bfv[4];
            #pragma unroll
            for (int i = 0; i < 4; ++i){
                const int ra = wOffM + i*16 + col;
                af[i]  = *(const bf16x8*)&Asb[ra*32 + (quad ^ ((ra >> 1) & 3))*8];
                const int rb = wOffN + i*16 + col;
                bfv[i] = *(const bf16x8*)&Wsb[rb*32 + (quad ^ ((rb >> 1) & 3))*8];
            }
            #pragma unroll
            for (int i = 0; i < 4; ++i)
                #pragma unroll
                for (int j = 0; j < 4; ++j)
                    acc[i][j] = __builtin_amdgcn_mfma_f32_16x16x32_bf16(af[i], bfv[j], acc[i][j], 0, 0, 0);
        }
    }

    // ---- LDS-staged epilogue ----
    __syncthreads();
    #pragma unroll
    for (int i = 0; i < 4; ++i){
        const int row0 = wOffM + i*16 + quad*4;
        #pragma unroll
        for (int j = 0; j < 4; ++j){
            const int cT = wOffN + j*16 + col;
            #pragma unroll
            for (int r = 0; r < 4; ++r)
                smem[(row0 + r)*132 + cT] = (bf16_t)acc[i][j][r];
        }
    }
    __syncthreads();

    const int half = n0 >> 11, within = n0 & 2047;
    bf16_t* dstBase = ((within < 1024) ? xy : z) + half*1024 + (within & 1023);
    #pragma unroll
    for (int k = 0; k < 8; ++k){
        const int idx = t + k*256;
        const int row = idx >> 4;
        const int ch  = (idx & 15) * 8;
        const int gm = m0 + row;
        if (gm < Mtot)
            *(bf16x8*)&dstBase[(size_t)gm*2048 + ch] = *(const bf16x8*)&smem[row*132 + ch];
    }
}

// ---------------------------------------------------------------------------
// Merged out-proj GEMM: A=y (M,2048), W K-concat (512,2048), C fp32.
// ---------------------------------------------------------------------------
__global__ __launch_bounds__(256) void gemm_out_kernel(
    const bf16_t* __restrict__ A, int Mtot,
    const bf16_t* __restrict__ W,
    float* __restrict__ C)
{
    __shared__ bf16_t As[2][128*32];
    __shared__ bf16_t Ws[2][128*32];
    const int t = threadIdx.x;
    const int lane = t & 63, w = t >> 6;
    const int m0 = blockIdx.x * 128, n0 = blockIdx.y * 128;
    const int rsub = lane >> 2, csub = lane & 3;
    const int col = lane & 15, quad = lane >> 4;
    const int wOffM = (w & 1) * 64, wOffN = (w >> 1) * 64;
    const int K = 2048;

    f32x4 acc[4][4];
    #pragma unroll
    for (int i = 0; i < 4; ++i)
        #pragma unroll
        for (int j = 0; j < 4; ++j)
            acc[i][j] = (f32x4){0.f, 0.f, 0.f, 0.f};

    for (int k0 = 0; k0 < K; k0 += 64){
        __syncthreads();
        #pragma unroll
        for (int hh = 0; hh < 2; ++hh){
            #pragma unroll
            for (int q = 0; q < 2; ++q){
                const int rt = w*32 + q*16 + rsub;
                const int lq = csub ^ ((rt >> 1) & 3);
                int ra = m0 + rt; ra = (ra < Mtot) ? ra : (Mtot - 1);
                const bf16_t* ga = A + (size_t)ra*K + k0 + hh*32 + lq*8;
                __builtin_amdgcn_global_load_lds(
                    (const __attribute__((address_space(1))) void*)ga,
                    (__attribute__((address_space(3))) void*)&As[hh][(w*32 + q*16)*32], 16, 0, 0);
                const bf16_t* gw = W + (size_t)(n0 + rt)*K + k0 + hh*32 + lq*8;
                __builtin_amdgcn_global_load_lds(
                    (const __attribute__((address_space(1))) void*)gw,
                    (__attribute__((address_space(3))) void*)&Ws[hh][(w*32 + q*16)*32], 16, 0, 0);
            }
        }
        __syncthreads();

        #pragma unroll
        for (int hh = 0; hh < 2; ++hh){
            bf16x8 af[4], bfv[4];
            #pragma unroll
            for (int i = 0; i < 4; ++i){
                const int ra = wOffM + i*16 + col;
                af[i]  = *(const bf16x8*)&As[hh][ra*32 + (quad ^ ((ra >> 1) & 3))*8];
                const int rb = wOffN + i*16 + col;
                bfv[i] = *(const bf16x8*)&Ws[hh][rb*32 + (quad ^ ((rb >> 1) & 3))*8];
            }
            #pragma unroll
            for (int i = 0; i < 4; ++i)
                #pragma unroll
                for (int j = 0; j < 4; ++j)
                    acc[i][j] = __builtin_amdgcn_mfma_f32_16x16x32_bf16(af[i], bfv[j], acc[i][j], 0, 0, 0);
        }
    }

    #pragma unroll
    for (int i = 0; i < 4; ++i){
        const int gmb = m0 + wOffM + i*16 + quad*4;
        #pragma unroll
        for (int j = 0; j < 4; ++j){
            const int gn = n0 + wOffN + j*16 + col;
            #pragma unroll
            for (int r = 0; r < 4; ++r){
                const int gm = gmb + r;
                if (gm < Mtot)
                    C[(size_t)gm*512 + gn] = acc[i][j][r];
            }
        }
    }
}

// ---------------------------------------------------------------------------
// Merged x-proj GEMM: y=0 fwd (N=64, C cols 0-63), y=1 bwd (N=48, cols 64-111).
// ---------------------------------------------------------------------------
__global__ __launch_bounds__(256) void gemm_x_kernel(
    const bf16_t* __restrict__ xc,
    const bf16_t* __restrict__ Wf, const bf16_t* __restrict__ Wb,
    float* __restrict__ C)
{
    __shared__ bf16_t As[128*32];
    __shared__ bf16_t Ws[64*32];
    const int half = blockIdx.y;
    const bf16_t* A = xc + half*1024;
    const bf16_t* W = half ? Wb : Wf;
    const int N = half ? 48 : 64;
    const int t = threadIdx.x;
    const int lane = t & 63, w = t >> 6;
    const int m0 = blockIdx.x * 128;
    const int rsub = lane >> 2, csub = lane & 3;
    const int col = lane & 15, quad = lane >> 4;

    f32x4 acc[2][4];
    #pragma unroll
    for (int i = 0; i < 2; ++i)
        #pragma unroll
        for (int j = 0; j < 4; ++j)
            acc[i][j] = (f32x4){0.f, 0.f, 0.f, 0.f};

    for (int k0 = 0; k0 < 1024; k0 += 32){
        __syncthreads();
        #pragma unroll
        for (int q = 0; q < 2; ++q){
            const int rt = q*64 + w*16 + rsub;
            const int lq = csub ^ ((rt >> 1) & 3);
            const bf16_t* ga = A + (size_t)(m0 + rt)*2048 + k0 + lq*8;
            __builtin_amdgcn_global_load_lds(
                (const __attribute__((address_space(1))) void*)ga,
                (__attribute__((address_space(3))) void*)&As[(q*64 + w*16)*32], 16, 0, 0);
        }
        {
            const int rt = w*16 + rsub;
            const int lq = csub ^ ((rt >> 1) & 3);
            int rw = (rt < N) ? rt : (N - 1);
            const bf16_t* gw = W + (size_t)rw*1024 + k0 + lq*8;
            __builtin_amdgcn_global_load_lds(
                (const __attribute__((address_space(1))) void*)gw,
                (__attribute__((address_space(3))) void*)&Ws[(w*16)*32], 16, 0, 0);
        }
        __syncthreads();

        bf16x8 af[2], bfv[4];
        #pragma unroll
        for (int i = 0; i < 2; ++i){
            const int ra = w*32 + i*16 + col;
            af[i]  = *(const bf16x8*)&As[ra*32 + (quad ^ ((ra >> 1) & 3))*8];
        }
        #pragma unroll
        for (int j = 0; j < 4; ++j){
            const int rb = j*16 + col;
            bfv[j] = *(const bf16x8*)&Ws[rb*32 + (quad ^ ((rb >> 1) & 3))*8];
        }
        #pragma unroll
        for (int i = 0; i < 2; ++i)
            #pragma unroll
            for (int j = 0; j < 4; ++j)
                acc[i][j] = __builtin_amdgcn_mfma_f32_16x16x32_bf16(af[i], bfv[j], acc[i][j], 0, 0, 0);
    }

    #pragma unroll
    for (int i = 0; i < 2; ++i){
        const int gmb = m0 + w*32 + i*16 + quad*4;
        #pragma unroll
        for (int j = 0; j < 4; ++j){
            const int gn = j*16 + col;
            if (gn < N){
                #pragma unroll
                for (int r = 0; r < 4; ++r)
                    C[(size_t)(gmb + r)*128 + half*64 + gn] = acc[i][j][r];
            }
        }
    }
}

// ---------------------------------------------------------------------------
// Merged dt projection: grid (M/16, 16); blockIdx.y<8 -> fwd, else bwd.
// Output goes to dto (M,2048) bf16.
// ---------------------------------------------------------------------------
__global__ __launch_bounds__(256) void dt_kernel(
    const float* __restrict__ xdb,   // (M, 128)
    const float* __restrict__ dtwf, const float* __restrict__ dtbf,
    const float* __restrict__ dtwb, const float* __restrict__ dtbb,
    bf16_t* __restrict__ dto)        // (M, 2048)
{
    const int half = blockIdx.y >> 3;
    const int d = (blockIdx.y & 7)*128 + (threadIdx.x & 127);
    const int mslot = threadIdx.x >> 7;
    const int m0 = blockIdx.x * 16;
    __shared__ float sd[16*32];
    for (int i = threadIdx.x; i < 16*32; i += 256){
        int r = i >> 5, c = i & 31;
        sd[i] = xdb[(size_t)(m0 + r)*128 + half*64 + c];
    }
    const float* dw = half ? dtwb : dtwf;
    float w[32];
    #pragma unroll
    for (int r = 0; r < 32; ++r) w[r] = dw[d*32 + r];
    const float db = half ? dtbb[d] : dtbf[d];
    __syncthreads();
    #pragma unroll
    for (int i = 0; i < 8; ++i){
        const int row = mslot + i*2;
        const float* rp = &sd[row*32];
        float a = db;
        #pragma unroll
        for (int r = 0; r < 32; ++r) a += w[r]*rp[r];
        dto[(size_t)(m0 + row)*2048 + half*1024 + d] = (bf16_t)softplusf_(a);
    }
}

// ---------------------------------------------------------------------------
// Depthwise conv + bias + silu, PARALLEL over L (FIR, not recurrent).
// ---------------------------------------------------------------------------
__global__ __launch_bounds__(256) void conv_silu_kernel(
    const bf16_t* __restrict__ xin,  // (M,2048)
    bf16_t* __restrict__ xout,       // (M,2048)
    const float* __restrict__ cwf, const float* __restrict__ cbf,
    const float* __restrict__ cwb, const float* __restrict__ cbb)
{
    const int gid = blockIdx.x*256 + threadIdx.x;   // Bc*10*2048 threads
    const int d2 = gid & 2047;
    const int rest = gid >> 11;
    const int b = rest / 10;
    const int g = rest - b*10;
    const int l0 = g*10;
    const int half = d2 >> 10, d = d2 & 1023;
    const bf16_t* in = xin + (size_t)b*SEQ*2048 + d2;
    bf16_t* outp = xout + (size_t)b*SEQ*2048 + d2;

    if (half == 0){
        const float w0 = cwf[d*4], w1 = cwf[d*4+1], w2 = cwf[d*4+2], w3 = cwf[d*4+3];
        const float bias = cbf[d];
        float v[13];
        #pragma unroll
        for (int i = 0; i < 13; ++i){
            const int l = l0 - 3 + i;
            v[i] = (l >= 0) ? (float)in[(size_t)l*2048] : 0.f;
        }
        #pragma unroll
        for (int i = 0; i < 10; ++i){
            const float a = bias + w0*v[i] + w1*v[i+1] + w2*v[i+2] + w3*v[i+3];
            outp[(size_t)(l0+i)*2048] = (bf16_t)siluf_(a);
        }
    } else {
        const float w0 = cwb[d*2], w1 = cwb[d*2+1];
        const float bias = cbb[d];
        float v[11];
        #pragma unroll
        for (int i = 0; i < 11; ++i){
            const int l = l0 + i;
            v[i] = (l < SEQ) ? (float)in[(size_t)l*2048] : 0.f;
        }
        #pragma unroll
        for (int i = 0; i < 10; ++i){
            const float a = bias + w1*v[i] + w0*v[i+1];
            outp[(size_t)(l0+i)*2048] = (bf16_t)siluf_(a);
        }
    }
}

// ---------------------------------------------------------------------------
// Selective scan v3: 4 threads per channel, LDS-staged inputs.
// Per block: 64 channels. x/dt packed as u32 pairs + z staged in LDS in
// 25-step quarters (coalesced, each value loaded from global once).
// Scan phase: 1 ds_read_b32 (imm offset) per step, unpack via shl/and
// (bf16->f32 is <<16, no cvt). B/C as f32x4/f32x2 LDS vector loads.
// ---------------------------------------------------------------------------
template<int DSS, int ROW, bool REV>
__device__ __forceinline__ void scan3_core(
    const ushort_t* __restrict__ xcB,   // block base (stride 2048 elems per l)
    const ushort_t* __restrict__ dtB,
    const ushort_t* __restrict__ zB,
    bf16_t* __restrict__ yB,            // per-thread channel base (write)
    const float* __restrict__ sx,       // B/C slab (indexed by global l)
    uint32_t* __restrict__ sxdt, ushort_t* __restrict__ szs,
    const float* __restrict__ Av, float Dd)
{
    const int t = threadIdx.x;
    const int sub = t & 3, chl = t >> 2;
    const bool wrr = (sub == 0);
    float h[DSS];
    #pragma unroll
    for (int j = 0; j < DSS; ++j) h[j] = 0.f;

    #pragma unroll 1
    for (int q = 0; q < 4; ++q){
        __syncthreads();
        // ---- stage 25 rows (each value loaded once, coalesced 128B/wave) ----
        for (int idx = t; idx < 25*64; idx += 256){
            const int r = idx >> 6, ch = idx & 63;
            const int s = q*25 + r;
            const int gl = REV ? (SEQ-1 - s) : s;
            const size_t off = (size_t)gl*2048 + ch;
            const uint32_t px = xcB[off];
            const uint32_t pt = dtB[off];
            sxdt[idx] = px | (pt << 16);
            szs[idx]  = zB[off];
        }
        __syncthreads();
        // ---- scan 25 steps from LDS ----
        int li = REV ? (SEQ-1 - q*25) : q*25;
        const int stp = REV ? -1 : 1;
        #pragma unroll 5
        for (int r = 0; r < 25; ++r){
            const uint32_t p = sxdt[r*64 + chl];
            const float xv   = __uint_as_float(p << 16);
            const float dtvv = __uint_as_float(p & 0xffff0000u);
            const float dtx  = dtvv * xv;
            float yv = 0.f;
            if (DSS == 4){
                const f32x4 Bv = *(const f32x4*)&sx[li*ROW + sub*4];
                const f32x4 Cv = *(const f32x4*)&sx[li*ROW + ROW/2 + sub*4];
                #pragma unroll
                for (int j = 0; j < 4; ++j){
                    h[j] = __expf(dtvv*Av[j])*h[j] + dtx*Bv[j];
                    yv += h[j]*Cv[j];
                }
            } else {
                const f32x2 Bv = *(const f32x2*)&sx[li*ROW + sub*2];
                const f32x2 Cv = *(const f32x2*)&sx[li*ROW + ROW/2 + sub*2];
                #pragma unroll
                for (int j = 0; j < 2; ++j){
                    h[j] = __expf(dtvv*Av[j])*h[j] + dtx*Bv[j];
                    yv += h[j]*Cv[j];
                }
            }
            yv += __shfl_xor(yv, 1);
            yv += __shfl_xor(yv, 2);
            if (wrr){
                const float zv = __uint_as_float(((uint32_t)szs[r*64 + chl]) << 16);
                float y = yv + xv*Dd;
                y *= siluf_(zv);
                yB[(size_t)li*2048] = (bf16_t)y;
            }
            li += stp;
        }
    }
}

__global__ __launch_bounds__(256) void scan_kernel(
    bf16_t* __restrict__ xc,         // conv-x in / y out (M,2048)
    const bf16_t* __restrict__ dtv,  // dt (M,2048)
    const bf16_t* __restrict__ z,    // (M,2048)
    const float* __restrict__ xdb,   // (b,SEQ,128)
    const float* __restrict__ Alogf, const float* __restrict__ Dpf,
    const float* __restrict__ Alogb, const float* __restrict__ Dpb)
{
    // blockIdx.x = b*32 + k;  k<16: fwd 64-ch block;  k>=16: bwd 64-ch block
    const int b = blockIdx.x >> 5, k = blockIdx.x & 31;
    const int t = threadIdx.x;
    const int sub = t & 3, chl = t >> 2;
    const bool fwd = (k < 16);

    __shared__ float sx[SEQ*32];          // B/C slab: fwd 12.8KB (bwd uses 16/row)
    __shared__ uint32_t sxdt[25*64];      // packed (x,dt) quarter: 6.4KB
    __shared__ ushort_t szs[25*64];       // z quarter: 3.2KB

    const float4* src = (const float4*)(xdb + (size_t)b*SEQ*128);
    if (fwd){
        float4* dst = (float4*)sx;
        for (int i = t; i < SEQ*8; i += 256){
            int row = i >> 3, c = i & 7;
            dst[row*8 + c] = src[row*32 + 8 + c];     // fwd B/C: floats 32..63
        }
    } else {
        float4* dst = (float4*)sx;
        for (int i = t; i < SEQ*4; i += 256){
            int row = i >> 2, c = i & 3;
            dst[row*4 + c] = src[row*32 + 24 + c];    // bwd B/C: floats 96..111
        }
    }
    // (first __syncthreads happens inside scan3_core before staging)

    if (fwd){
        const int d0 = k*64;
        const int d = d0 + chl;                       // 0..1023
        const size_t boff = (size_t)b*SEQ*2048 + d0;
        float Av[4];
        #pragma unroll
        for (int j = 0; j < 4; ++j) Av[j] = -__expf(Alogf[d*16 + sub*4 + j]);
        scan3_core<4, 32, false>((const ushort_t*)xc + boff,
                                 (const ushort_t*)dtv + boff,
                                 (const ushort_t*)z + boff,
                                 xc + boff + chl,
                                 sx, sxdt, szs, Av, Dpf[d]);
    } else {
        const int d0 = (k - 16)*64;
        const int d = d0 + chl;                       // 0..1023
        const size_t boff = (size_t)b*SEQ*2048 + 1024 + d0;
        float Av[2];
        #pragma unroll
        for (int j = 0; j < 2; ++j) Av[j] = -__expf(Alogb[d*8 + sub*2 + j]);
        scan3_core<2, 16, true>((const ushort_t*)xc + boff,
                                (const ushort_t*)dtv + boff,
                                (const ushort_t*)z + boff,
                                xc + boff + chl,
                                sx, sxdt, szs, Av, Dpb[d]);
    }
}

// ---------------------------------------------------------------------------
// Max-pool over L, split out of head for 4x block parallelism.
// ---------------------------------------------------------------------------
__global__ __launch_bounds__(256) void pool_kernel(
    const float* __restrict__ acc,   // (Bc, L, 512)
    float* __restrict__ pooled)      // (Bc, 512)
{
    const int b = blockIdx.x, y = blockIdx.y;
    const int c = y*128 + (threadIdx.x & 127);
    const int half = threadIdx.x >> 7;
    const float* base = acc + (size_t)b*SEQ*512 + c;
    float m = -3.4e38f;
    #pragma unroll 5
    for (int l = half*50; l < half*50 + 50; ++l)
        m = fmaxf(m, base[(size_t)l*512]);
    __shared__ float sm[256];
    sm[threadIdx.x] = m;
    __syncthreads();
    if (half == 0)
        pooled[(size_t)b*512 + c] = fmaxf(sm[threadIdx.x], sm[threadIdx.x + 128]);
}

// ---------------------------------------------------------------------------
// Head: LN(512), fc1(512->128)+relu, fc2(128->4) on pooled vector
// ---------------------------------------------------------------------------
__global__ __launch_bounds__(256) void head_kernel(
    const float* __restrict__ pooled,  // (Bc, 512)
    const float* __restrict__ ng, const float* __restrict__ nb,
    const float* __restrict__ w1, const float* __restrict__ b1,
    const float* __restrict__ w2, const float* __restrict__ b2,
    float* __restrict__ out)           // (Bc, 4) chunk base
{
    const int b = blockIdx.x, t = threadIdx.x;
    __shared__ float sp[512];
    __shared__ float sh2[256];
    __shared__ float sh[128];
    __shared__ float red1[4], red2[4];

    float s1 = 0.f, s2 = 0.f;
    for (int o = t; o < 512; o += 256){
        float v = pooled[(size_t)b*512 + o];
        sp[o] = v; s1 += v; s2 += v*v;
    }
    #pragma unroll
    for (int off = 32; off > 0; off >>= 1){ s1 += __shfl_xor(s1, off); s2 += __shfl_xor(s2, off); }
    const int wv = t >> 6, lane = t & 63;
    if (lane == 0){ red1[wv] = s1; red2[wv] = s2; }
    __syncthreads();
    if (t == 0){
        float a = 0.f, c = 0.f;
        for (int i = 0; i < 4; ++i){ a += red1[i]; c += red2[i]; }
        float mean = a * (1.f/512.f);
        float var = c * (1.f/512.f) - mean*mean;
        red1[0] = mean; red2[0] = rsqrtf(var + 1e-5f);
    }
    __syncthreads();
    const float mean = red1[0], rstd = red2[0];
    for (int o = t; o < 512; o += 256) sp[o] = (sp[o]-mean)*rstd*ng[o] + nb[o];
    __syncthreads();

    {
        const int o = t & 127, half = t >> 7;
        const float4* wrow = (const float4*)(w1 + (size_t)o*512 + half*256);
        const float4* sp4 = (const float4*)sp + half*64;
        float s = 0.f;
        #pragma unroll 8
        for (int j = 0; j < 64; ++j){
            float4 a = sp4[j], wq = wrow[j];
            s += a.x*wq.x + a.y*wq.y + a.z*wq.z + a.w*wq.w;
        }
        sh2[t] = s;
    }
    __syncthreads();
    if (t < 128) sh[t] = fmaxf(sh2[t] + sh2[t + 128] + b1[t], 0.f);
    __syncthreads();
    if (t < 4){
        float a = b2[t];
        for (int j = 0; j < 128; ++j) a += sh[j]*w2[t*128 + j];
        out[b*4 + t] = a;
    }
}

// ---------------------------------------------------------------------------
extern "C" void kernel_launch(void* const* d_in, const int* in_sizes, int n_in,
                              void* d_out, int out_size, void* d_ws, size_t ws_size,
                              hipStream_t stream)
{
    (void)in_sizes; (void)n_in; (void)out_size;
    const float* x        = (const float*)d_in[0];
    const float* fe_w     = (const float*)d_in[1];
    const float* fe_b     = (const float*)d_in[2];
    const float* fe_ln_g  = (const float*)d_in[3];
    const float* fe_ln_b  = (const float*)d_in[4];
    const float* emb_ln_g = (const float*)d_in[5];
    const float* emb_ln_b = (const float*)d_in[6];
    const float* conv1_w  = (const float*)d_in[7];
    const float* conv1_b  = (const float*)d_in[8];
    const float* conv2_w  = (const float*)d_in[9];
    const float* conv2_b  = (const float*)d_in[10];
    const float* mf_in_w  = (const float*)d_in[11];
    const float* mf_conv_w= (const float*)d_in[12];
    const float* mf_conv_b= (const float*)d_in[13];
    const float* mf_xproj = (const float*)d_in[14];
    const float* mf_dt_w  = (const float*)d_in[15];
    const float* mf_dt_b  = (const float*)d_in[16];
    const float* mf_Alog  = (const float*)d_in[17];
    const float* mf_D     = (const float*)d_in[18];
    const float* mf_out_w = (const float*)d_in[19];
    const float* mb_in_w  = (const float*)d_in[20];
    const float* mb_conv_w= (const float*)d_in[21];
    const float* mb_conv_b= (const float*)d_in[22];
    const float* mb_xproj = (const float*)d_in[23];
    const float* mb_dt_w  = (const float*)d_in[24];
    const float* mb_dt_b  = (const float*)d_in[25];
    const float* mb_Alog  = (const float*)d_in[26];
    const float* mb_D     = (const float*)d_in[27];
    const float* mb_out_w = (const float*)d_in[28];
    const float* norm_g   = (const float*)d_in[29];
    const float* norm_b   = (const float*)d_in[30];
    const float* fc1_w    = (const float*)d_in[31];
    const float* fc1_b    = (const float*)d_in[32];
    const float* fc2_w    = (const float*)d_in[33];
    const float* fc2_b    = (const float*)d_in[34];
    float* out = (float*)d_out;

    // ---- fixed workspace region ----
    char* p = (char*)d_ws;
    bf16_t* w_in   = (bf16_t*)p; p += (size_t)4096*512*sizeof(bf16_t);   // [mf; mb]
    bf16_t* w_out  = (bf16_t*)p; p += (size_t)512*2048*sizeof(bf16_t);   // K-concat
    bf16_t* w_xpf  = (bf16_t*)p; p += (size_t)64*1024*sizeof(bf16_t);
    bf16_t* w_xpb  = (bf16_t*)p; p += (size_t)48*1024*sizeof(bf16_t);
    bf16_t* W1p    = (bf16_t*)p; p += (size_t)128*96*sizeof(bf16_t);
    bf16_t* W2p    = (bf16_t*)p; p += (size_t)256*384*sizeof(bf16_t);
    bf16_t* comb_all = (bf16_t*)p; p += (size_t)BSZ*SEQ*512*sizeof(bf16_t);
    const size_t fixed_bytes = (size_t)(p - (char*)d_ws);

    // ---- chunk region ----
    const size_t per_b = (size_t)SEQ * (2048*2 + 2048*2 + 2048*2 + 128*4);
    const size_t budget = (ws_size > fixed_bytes) ? (ws_size - fixed_bytes) : 0;
    int Bc = BSZ;
    while (Bc > 64 && (size_t)Bc * per_b > budget) Bc >>= 1;   // Bc in {512,256,128,64}
    const int nch = BSZ / Bc;
    const int M = Bc * SEQ;

    bf16_t* F0pad = (bf16_t*)p;   // aliases chunk region (pre-loop only)
    bf16_t* F1pad = F0pad + (size_t)BSZ*102*32;
    bf16_t* xy   = (bf16_t*)p;               p += (size_t)M*2048*sizeof(bf16_t);
    bf16_t* z    = (bf16_t*)p;               p += (size_t)M*2048*sizeof(bf16_t);
    bf16_t* dtb  = (bf16_t*)p;               p += (size_t)M*2048*sizeof(bf16_t);
    float*  xdb  = (float*)p;
    // Buffer plan per chunk:
    //   gemm_in: comb -> xy(raw x), z
    //   conv:    xy -> dtb (xc = conv+silu x)      [dtb free here]
    //   gemm_x:  dtb -> xdb                        [raw x in xy now dead]
    //   dt:      xdb -> xy (dt values)
    //   scan:    reads dtb(xc), xy(dt), z, xdb; writes y in place into dtb
    //   gemm_out: dtb(y) -> accb = (float*)xy      [dt dead after scan]
    //   pool:    (float*)xy -> xdb;  head: xdb -> out
    float*  accb = (float*)xy;

    // ---- weight conversions / rearrange ----
    cvt_bf16_kernel<<<(2048*512+255)/256, 256, 0, stream>>>(mf_in_w, w_in, 2048*512);
    cvt_bf16_kernel<<<(2048*512+255)/256, 256, 0, stream>>>(mb_in_w, w_in + (size_t)2048*512, 2048*512);
    prep_outw_kernel<<<(512*2048+255)/256, 256, 0, stream>>>(mf_out_w, mb_out_w, w_out);
    cvt_bf16_kernel<<<(64*1024+255)/256,  256, 0, stream>>>(mf_xproj, w_xpf, 64*1024);
    cvt_bf16_kernel<<<(48*1024+255)/256,  256, 0, stream>>>(mb_xproj, w_xpb, 48*1024);
    prep_convw_kernel<<<(256*384+255)/256, 256, 0, stream>>>(conv1_w, conv2_w, W1p, W2p);

    // ---- front-end ----
    fe0_kernel<<<BSZ, 256, 0, stream>>>(x, fe_w, fe_b, fe_ln_g, fe_ln_b,
        emb_ln_g, emb_ln_b, comb_all, F0pad, F1pad);
    gemm_conv_kernel<<<dim3(1, 1, BSZ), 256, 0, stream>>>(
        F0pad, 32, 102*32, W1p, 96, 128, conv1_b, F1pad, 128, 102, 1, 0, SEQ);
    gemm_conv_kernel<<<dim3(1, 2, BSZ), 256, 0, stream>>>(
        F1pad, 128, 102*128, W2p, 384, 256, conv2_b, comb_all, 512, 100, 0, 256, SEQ);

    const int gm128 = M / 128;

    for (int c = 0; c < nch; ++c){
        const size_t b0 = (size_t)c * Bc;
        const bf16_t* comb = comb_all + b0*SEQ*512;

        gemm_in_kernel<<<dim3(gm128, 32), 256, 0, stream>>>(comb, 512, M, w_in, 512, xy, z);
        conv_silu_kernel<<<Bc*80, 256, 0, stream>>>(xy, dtb, mf_conv_w, mf_conv_b,
                                                    mb_conv_w, mb_conv_b);
        gemm_x_kernel<<<dim3(gm128, 2), 256, 0, stream>>>(dtb, w_xpf, w_xpb, xdb);
        dt_kernel<<<dim3(M/16, 16), 256, 0, stream>>>(xdb, mf_dt_w, mf_dt_b,
                                                      mb_dt_w, mb_dt_b, xy);
        scan_kernel<<<Bc*32, 256, 0, stream>>>(dtb, xy, z, xdb,
                                               mf_Alog, mf_D, mb_Alog, mb_D);
        gemm_out_kernel<<<dim3(gm128, 4), 256, 0, stream>>>(dtb, M, w_out, accb);
        pool_kernel<<<dim3(Bc, 4), 256, 0, stream>>>(accb, xdb);
        head_kernel<<<Bc, 256, 0, stream>>>(xdb, norm_g, norm_b, fc1_w, fc1_b,
                                            fc2_w, fc2_b, out + b0*4);
    }
}

// Round 5
// 1537.131 us; speedup vs baseline: 1.1901x; 1.1901x over previous
//
#include <hip/hip_runtime.h>
#include <cstddef>
#include <cstdint>

#define BSZ 512
#define SEQ 100

typedef __bf16 bf16_t;
typedef __attribute__((ext_vector_type(8))) __bf16 bf16x8;
typedef __attribute__((ext_vector_type(4))) float f32x4;
typedef unsigned short ushort_t;

__device__ __forceinline__ float sigmoidf_(float v){ return 1.f/(1.f + __expf(-v)); }
__device__ __forceinline__ float siluf_(float v){ return v * sigmoidf_(v); }
__device__ __forceinline__ float softplusf_(float v){ return (v > 20.f) ? v : __logf(1.f + __expf(v)); }

// ---------------------------------------------------------------------------
__global__ __launch_bounds__(256) void cvt_bf16_kernel(
    const float* __restrict__ src, bf16_t* __restrict__ dst, int n)
{
    int i = blockIdx.x*256 + threadIdx.x;
    if (i < n) dst[i] = (bf16_t)src[i];
}

__global__ __launch_bounds__(256) void prep_outw_kernel(
    const float* __restrict__ of, const float* __restrict__ ob, bf16_t* __restrict__ W)
{
    int i = blockIdx.x*256 + threadIdx.x;
    if (i < 512*2048){
        int o = i >> 11, k = i & 2047;
        W[i] = (bf16_t)((k < 1024) ? of[o*1024 + k] : ob[o*1024 + (k - 1024)]);
    }
}

__global__ __launch_bounds__(256) void prep_convw_kernel(
    const float* __restrict__ c1w, const float* __restrict__ c2w,
    bf16_t* __restrict__ W1p, bf16_t* __restrict__ W2p)
{
    int i = blockIdx.x*256 + threadIdx.x;
    if (i < 128*96){
        int o = i / 96, kk = i - o*96, k = kk >> 5, c = kk & 31;
        W1p[i] = (c < 22) ? (bf16_t)c1w[(o*22 + c)*3 + k] : (bf16_t)0.f;
    }
    if (i < 256*384){
        int o = i / 384, kk = i - o*384, k = kk >> 7, c = kk & 127;
        W2p[i] = (bf16_t)c2w[(o*128 + c)*3 + k];
    }
}

// ---------------------------------------------------------------------------
// FE0: id-embed (2 LN) -> comb[...,0:256]; build F0pad; zero F1pad boundary.
// ---------------------------------------------------------------------------
__global__ __launch_bounds__(256) void fe0_kernel(
    const float* __restrict__ x,
    const float* __restrict__ fe_w, const float* __restrict__ fe_b,
    const float* __restrict__ g1, const float* __restrict__ b1,
    const float* __restrict__ g2, const float* __restrict__ b2,
    bf16_t* __restrict__ comb, bf16_t* __restrict__ F0pad, bf16_t* __restrict__ F1pad)
{
    const int b = blockIdx.x;
    const int t = threadIdx.x;
    const int wv = t >> 6, lane = t & 63;

    float few[4], feb[4], lg1[4], lb1[4], lg2[4], lb2[4];
    #pragma unroll
    for (int q = 0; q < 4; ++q){
        int j = lane + 64*q;
        few[q] = fe_w[j]; feb[q] = fe_b[j];
        lg1[q] = g1[j];  lb1[q] = b1[j];
        lg2[q] = g2[j];  lb2[q] = b2[j];
    }
    for (int l = wv; l < SEQ; l += 4){
        float m = fabsf(x[(size_t)(b*SEQ + l)*23]);
        float e[4];
        float s1 = 0.f, s2 = 0.f;
        #pragma unroll
        for (int q = 0; q < 4; ++q){ e[q] = m*few[q] + feb[q]; s1 += e[q]; s2 += e[q]*e[q]; }
        #pragma unroll
        for (int off = 32; off > 0; off >>= 1){ s1 += __shfl_xor(s1, off); s2 += __shfl_xor(s2, off); }
        float mean = s1 * (1.f/256.f);
        float rstd = rsqrtf(s2*(1.f/256.f) - mean*mean + 1e-5f);
        s1 = 0.f; s2 = 0.f;
        #pragma unroll
        for (int q = 0; q < 4; ++q){
            e[q] = fmaxf((e[q]-mean)*rstd*lg1[q] + lb1[q], 0.f);
            s1 += e[q]; s2 += e[q]*e[q];
        }
        #pragma unroll
        for (int off = 32; off > 0; off >>= 1){ s1 += __shfl_xor(s1, off); s2 += __shfl_xor(s2, off); }
        mean = s1 * (1.f/256.f);
        rstd = rsqrtf(s2*(1.f/256.f) - mean*mean + 1e-5f);
        #pragma unroll
        for (int q = 0; q < 4; ++q){
            float v = fmaxf((e[q]-mean)*rstd*lg2[q] + lb2[q], 0.f);
            comb[(size_t)(b*SEQ + l)*512 + lane + 64*q] = (bf16_t)v;
        }
    }

    for (int idx = t; idx < 102*32; idx += 256){
        int r = idx >> 5, c = idx & 31;
        float v = 0.f;
        if (r >= 1 && r <= SEQ && c < 22) v = x[(size_t)(b*SEQ + r - 1)*23 + 1 + c];
        F0pad[(size_t)(b*102 + r)*32 + c] = (bf16_t)v;
    }
    if (t < 128) F1pad[(size_t)(b*102 + 0)*128 + t] = (bf16_t)0.f;
    else F1pad[(size_t)(b*102 + 101)*128 + (t - 128)] = (bf16_t)0.f;
}

// ---------------------------------------------------------------------------
// Conv-as-GEMM (z-batched): C[m,n] = relu(sum_k A_z[m*lda + k]*W[n,k] + bias[n])
// ---------------------------------------------------------------------------
__global__ __launch_bounds__(256) void gemm_conv_kernel(
    const bf16_t* __restrict__ Abase, int lda, int Az,
    const bf16_t* __restrict__ W, int K, int N,
    const float* __restrict__ bias,
    bf16_t* __restrict__ Cbase, int ldc, int Cb, int coff, int noff, int Mtot)
{
    __shared__ bf16_t As[128*32];
    __shared__ bf16_t Ws[128*32];
    const bf16_t* A = Abase + (size_t)blockIdx.z * Az;
    const int t = threadIdx.x;
    const int lane = t & 63, w = t >> 6;
    const int n0 = blockIdx.y * 128;
    const int rsub = lane >> 2, csub = lane & 3;
    const int col = lane & 15, quad = lane >> 4;
    const int wOffM = (w & 1) * 64, wOffN = (w >> 1) * 64;

    f32x4 acc[4][4];
    #pragma unroll
    for (int i = 0; i < 4; ++i)
        #pragma unroll
        for (int j = 0; j < 4; ++j)
            acc[i][j] = (f32x4){0.f, 0.f, 0.f, 0.f};

    for (int k0 = 0; k0 < K; k0 += 32){
        __syncthreads();
        #pragma unroll
        for (int q = 0; q < 2; ++q){
            const int rt = w*32 + q*16 + rsub;
            const int lq = csub ^ ((rt >> 1) & 3);
            int ra = (rt < Mtot) ? rt : (Mtot - 1);
            const bf16_t* ga = A + (size_t)ra*lda + k0 + lq*8;
            __builtin_amdgcn_global_load_lds(
                (const __attribute__((address_space(1))) void*)ga,
                (__attribute__((address_space(3))) void*)&As[(w*32 + q*16)*32], 16, 0, 0);
            const bf16_t* gw = W + (size_t)(n0 + rt)*K + k0 + lq*8;
            __builtin_amdgcn_global_load_lds(
                (const __attribute__((address_space(1))) void*)gw,
                (__attribute__((address_space(3))) void*)&Ws[(w*32 + q*16)*32], 16, 0, 0);
        }
        __syncthreads();

        bf16x8 af[4], bfv[4];
        #pragma unroll
        for (int i = 0; i < 4; ++i){
            const int ra = wOffM + i*16 + col;
            af[i]  = *(const bf16x8*)&As[ra*32 + (quad ^ ((ra >> 1) & 3))*8];
            const int rb = wOffN + i*16 + col;
            bfv[i] = *(const bf16x8*)&Ws[rb*32 + (quad ^ ((rb >> 1) & 3))*8];
        }
        #pragma unroll
        for (int i = 0; i < 4; ++i)
            #pragma unroll
            for (int j = 0; j < 4; ++j)
                acc[i][j] = __builtin_amdgcn_mfma_f32_16x16x32_bf16(af[i], bfv[j], acc[i][j], 0, 0, 0);
    }

    #pragma unroll
    for (int i = 0; i < 4; ++i){
        const int gmb = wOffM + i*16 + quad*4;
        #pragma unroll
        for (int j = 0; j < 4; ++j){
            const int gn = n0 + wOffN + j*16 + col;
            const float bb = bias[gn];
            #pragma unroll
            for (int r = 0; r < 4; ++r){
                const int gm = gmb + r;
                if (gm < Mtot){
                    float v = fmaxf(acc[i][j][r] + bb, 0.f);
                    Cbase[((size_t)blockIdx.z*Cb + coff + gm)*ldc + noff + gn] = (bf16_t)v;
                }
            }
        }
    }
}

// ---------------------------------------------------------------------------
// Merged in-proj GEMM: A=comb (M,512), W=[mf_in; mb_in] (4096,512).
// ---------------------------------------------------------------------------
__global__ __launch_bounds__(256) void gemm_in_kernel(
    const bf16_t* __restrict__ A, int lda, int Mtot,
    const bf16_t* __restrict__ W, int K,
    bf16_t* __restrict__ xy, bf16_t* __restrict__ z)
{
    __shared__ bf16_t smem[128*132];          // 33,792 B; staging uses first 32 KB
    bf16_t* As0 = smem;
    bf16_t* As1 = smem + 4096;
    bf16_t* Ws0 = smem + 8192;
    bf16_t* Ws1 = smem + 12288;
    const int t = threadIdx.x;
    const int lane = t & 63, w = t >> 6;
    const int m0 = blockIdx.x * 128, n0 = blockIdx.y * 128;
    const int rsub = lane >> 2, csub = lane & 3;
    const int col = lane & 15, quad = lane >> 4;
    const int wOffM = (w & 1) * 64, wOffN = (w >> 1) * 64;

    f32x4 acc[4][4];
    #pragma unroll
    for (int i = 0; i < 4; ++i)
        #pragma unroll
        for (int j = 0; j < 4; ++j)
            acc[i][j] = (f32x4){0.f, 0.f, 0.f, 0.f};

    for (int k0 = 0; k0 < K; k0 += 64){
        __syncthreads();
        #pragma unroll
        for (int hh = 0; hh < 2; ++hh){
            bf16_t* Asb = hh ? As1 : As0;
            bf16_t* Wsb = hh ? Ws1 : Ws0;
            #pragma unroll
            for (int q = 0; q < 2; ++q){
                const int rt = w*32 + q*16 + rsub;
                const int lq = csub ^ ((rt >> 1) & 3);
                int ra = m0 + rt; ra = (ra < Mtot) ? ra : (Mtot - 1);
                const bf16_t* ga = A + (size_t)ra*lda + k0 + hh*32 + lq*8;
                __builtin_amdgcn_global_load_lds(
                    (const __attribute__((address_space(1))) void*)ga,
                    (__attribute__((address_space(3))) void*)&Asb[(w*32 + q*16)*32], 16, 0, 0);
                const bf16_t* gw = W + (size_t)(n0 + rt)*K + k0 + hh*32 + lq*8;
                __builtin_amdgcn_global_load_lds(
                    (const __attribute__((address_space(1))) void*)gw,
                    (__attribute__((address_space(3))) void*)&Wsb[(w*32 + q*16)*32], 16, 0, 0);
            }
        }
        __syncthreads();

        #pragma unroll
        for (int hh = 0; hh < 2; ++hh){
            bf16_t* Asb = hh ? As1 : As0;
            bf16_t* Wsb = hh ? Ws1 : Ws0;
            bf16x8 af[4], bfv[4];
            #pragma unroll
            for (int i = 0; i < 4; ++i){
                const int ra = wOffM + i*16 + col;
                af[i]  = *(const bf16x8*)&Asb[ra*32 + (quad ^ ((ra >> 1) & 3))*8];
                const int rb = wOffN + i*16 + col;
                bfv[i] = *(const bf16x8*)&Wsb[rb*32 + (quad ^ ((rb >> 1) & 3))*8];
            }
            #pragma unroll
            for (int i = 0; i < 4; ++i)
                #pragma unroll
                for (int j = 0; j < 4; ++j)
                    acc[i][j] = __builtin_amdgcn_mfma_f32_16x16x32_bf16(af[i], bfv[j], acc[i][j], 0, 0, 0);
        }
    }

    // ---- LDS-staged epilogue ----
    __syncthreads();
    #pragma unroll
    for (int i = 0; i < 4; ++i){
        const int row0 = wOffM + i*16 + quad*4;
        #pragma unroll
        for (int j = 0; j < 4; ++j){
            const int cT = wOffN + j*16 + col;
            #pragma unroll
            for (int r = 0; r < 4; ++r)
                smem[(row0 + r)*132 + cT] = (bf16_t)acc[i][j][r];
        }
    }
    __syncthreads();

    const int half = n0 >> 11, within = n0 & 2047;
    bf16_t* dstBase = ((within < 1024) ? xy : z) + half*1024 + (within & 1023);
    #pragma unroll
    for (int k = 0; k < 8; ++k){
        const int idx = t + k*256;
        const int row = idx >> 4;
        const int ch  = (idx & 15) * 8;
        const int gm = m0 + row;
        if (gm < Mtot)
            *(bf16x8*)&dstBase[(size_t)gm*2048 + ch] = *(const bf16x8*)&smem[row*132 + ch];
    }
}

// ---------------------------------------------------------------------------
// Merged out-proj GEMM: A=y (M,2048), W K-concat (512,2048), C fp32.
// ---------------------------------------------------------------------------
__global__ __launch_bounds__(256) void gemm_out_kernel(
    const bf16_t* __restrict__ A, int Mtot,
    const bf16_t* __restrict__ W,
    float* __restrict__ C)
{
    __shared__ bf16_t As[2][128*32];
    __shared__ bf16_t Ws[2][128*32];
    const int t = threadIdx.x;
    const int lane = t & 63, w = t >> 6;
    const int m0 = blockIdx.x * 128, n0 = blockIdx.y * 128;
    const int rsub = lane >> 2, csub = lane & 3;
    const int col = lane & 15, quad = lane >> 4;
    const int wOffM = (w & 1) * 64, wOffN = (w >> 1) * 64;
    const int K = 2048;

    f32x4 acc[4][4];
    #pragma unroll
    for (int i = 0; i < 4; ++i)
        #pragma unroll
        for (int j = 0; j < 4; ++j)
            acc[i][j] = (f32x4){0.f, 0.f, 0.f, 0.f};

    for (int k0 = 0; k0 < K; k0 += 64){
        __syncthreads();
        #pragma unroll
        for (int hh = 0; hh < 2; ++hh){
            #pragma unroll
            for (int q = 0; q < 2; ++q){
                const int rt = w*32 + q*16 + rsub;
                const int lq = csub ^ ((rt >> 1) & 3);
                int ra = m0 + rt; ra = (ra < Mtot) ? ra : (Mtot - 1);
                const bf16_t* ga = A + (size_t)ra*K + k0 + hh*32 + lq*8;
                __builtin_amdgcn_global_load_lds(
                    (const __attribute__((address_space(1))) void*)ga,
                    (__attribute__((address_space(3))) void*)&As[hh][(w*32 + q*16)*32], 16, 0, 0);
                const bf16_t* gw = W + (size_t)(n0 + rt)*K + k0 + hh*32 + lq*8;
                __builtin_amdgcn_global_load_lds(
                    (const __attribute__((address_space(1))) void*)gw,
                    (__attribute__((address_space(3))) void*)&Ws[hh][(w*32 + q*16)*32], 16, 0, 0);
            }
        }
        __syncthreads();

        #pragma unroll
        for (int hh = 0; hh < 2; ++hh){
            bf16x8 af[4], bfv[4];
            #pragma unroll
            for (int i = 0; i < 4; ++i){
                const int ra = wOffM + i*16 + col;
                af[i]  = *(const bf16x8*)&As[hh][ra*32 + (quad ^ ((ra >> 1) & 3))*8];
                const int rb = wOffN + i*16 + col;
                bfv[i] = *(const bf16x8*)&Ws[hh][rb*32 + (quad ^ ((rb >> 1) & 3))*8];
            }
            #pragma unroll
            for (int i = 0; i < 4; ++i)
                #pragma unroll
                for (int j = 0; j < 4; ++j)
                    acc[i][j] = __builtin_amdgcn_mfma_f32_16x16x32_bf16(af[i], bfv[j], acc[i][j], 0, 0, 0);
        }
    }

    #pragma unroll
    for (int i = 0; i < 4; ++i){
        const int gmb = m0 + wOffM + i*16 + quad*4;
        #pragma unroll
        for (int j = 0; j < 4; ++j){
            const int gn = n0 + wOffN + j*16 + col;
            #pragma unroll
            for (int r = 0; r < 4; ++r){
                const int gm = gmb + r;
                if (gm < Mtot)
                    C[(size_t)gm*512 + gn] = acc[i][j][r];
            }
        }
    }
}

// ---------------------------------------------------------------------------
// Merged x-proj GEMM: y=0 fwd (N=64, C cols 0-63), y=1 bwd (N=48, cols 64-111).
// ---------------------------------------------------------------------------
__global__ __launch_bounds__(256) void gemm_x_kernel(
    const bf16_t* __restrict__ xc,
    const bf16_t* __restrict__ Wf, const bf16_t* __restrict__ Wb,
    float* __restrict__ C)
{
    __shared__ bf16_t As[128*32];
    __shared__ bf16_t Ws[64*32];
    const int half = blockIdx.y;
    const bf16_t* A = xc + half*1024;
    const bf16_t* W = half ? Wb : Wf;
    const int N = half ? 48 : 64;
    const int t = threadIdx.x;
    const int lane = t & 63, w = t >> 6;
    const int m0 = blockIdx.x * 128;
    const int rsub = lane >> 2, csub = lane & 3;
    const int col = lane & 15, quad = lane >> 4;

    f32x4 acc[2][4];
    #pragma unroll
    for (int i = 0; i < 2; ++i)
        #pragma unroll
        for (int j = 0; j < 4; ++j)
            acc[i][j] = (f32x4){0.f, 0.f, 0.f, 0.f};

    for (int k0 = 0; k0 < 1024; k0 += 32){
        __syncthreads();
        #pragma unroll
        for (int q = 0; q < 2; ++q){
            const int rt = q*64 + w*16 + rsub;
            const int lq = csub ^ ((rt >> 1) & 3);
            const bf16_t* ga = A + (size_t)(m0 + rt)*2048 + k0 + lq*8;
            __builtin_amdgcn_global_load_lds(
                (const __attribute__((address_space(1))) void*)ga,
                (__attribute__((address_space(3))) void*)&As[(q*64 + w*16)*32], 16, 0, 0);
        }
        {
            const int rt = w*16 + rsub;
            const int lq = csub ^ ((rt >> 1) & 3);
            int rw = (rt < N) ? rt : (N - 1);
            const bf16_t* gw = W + (size_t)rw*1024 + k0 + lq*8;
            __builtin_amdgcn_global_load_lds(
                (const __attribute__((address_space(1))) void*)gw,
                (__attribute__((address_space(3))) void*)&Ws[(w*16)*32], 16, 0, 0);
        }
        __syncthreads();

        bf16x8 af[2], bfv[4];
        #pragma unroll
        for (int i = 0; i < 2; ++i){
            const int ra = w*32 + i*16 + col;
            af[i]  = *(const bf16x8*)&As[ra*32 + (quad ^ ((ra >> 1) & 3))*8];
        }
        #pragma unroll
        for (int j = 0; j < 4; ++j){
            const int rb = j*16 + col;
            bfv[j] = *(const bf16x8*)&Ws[rb*32 + (quad ^ ((rb >> 1) & 3))*8];
        }
        #pragma unroll
        for (int i = 0; i < 2; ++i)
            #pragma unroll
            for (int j = 0; j < 4; ++j)
                acc[i][j] = __builtin_amdgcn_mfma_f32_16x16x32_bf16(af[i], bfv[j], acc[i][j], 0, 0, 0);
    }

    #pragma unroll
    for (int i = 0; i < 2; ++i){
        const int gmb = m0 + w*32 + i*16 + quad*4;
        #pragma unroll
        for (int j = 0; j < 4; ++j){
            const int gn = j*16 + col;
            if (gn < N){
                #pragma unroll
                for (int r = 0; r < 4; ++r)
                    C[(size_t)(gmb + r)*128 + half*64 + gn] = acc[i][j][r];
            }
        }
    }
}

// ---------------------------------------------------------------------------
// Merged dt projection: grid (M/16, 16); blockIdx.y<8 -> fwd, else bwd.
// ---------------------------------------------------------------------------
__global__ __launch_bounds__(256) void dt_kernel(
    const float* __restrict__ xdb,   // (M, 128)
    const float* __restrict__ dtwf, const float* __restrict__ dtbf,
    const float* __restrict__ dtwb, const float* __restrict__ dtbb,
    bf16_t* __restrict__ dto)        // (M, 2048)
{
    const int half = blockIdx.y >> 3;
    const int d = (blockIdx.y & 7)*128 + (threadIdx.x & 127);
    const int mslot = threadIdx.x >> 7;
    const int m0 = blockIdx.x * 16;
    __shared__ float sd[16*32];
    for (int i = threadIdx.x; i < 16*32; i += 256){
        int r = i >> 5, c = i & 31;
        sd[i] = xdb[(size_t)(m0 + r)*128 + half*64 + c];
    }
    const float* dw = half ? dtwb : dtwf;
    float w[32];
    #pragma unroll
    for (int r = 0; r < 32; ++r) w[r] = dw[d*32 + r];
    const float db = half ? dtbb[d] : dtbf[d];
    __syncthreads();
    #pragma unroll
    for (int i = 0; i < 8; ++i){
        const int row = mslot + i*2;
        const float* rp = &sd[row*32];
        float a = db;
        #pragma unroll
        for (int r = 0; r < 32; ++r) a += w[r]*rp[r];
        dto[(size_t)(m0 + row)*2048 + half*1024 + d] = (bf16_t)softplusf_(a);
    }
}

// ---------------------------------------------------------------------------
// Depthwise conv + bias + silu, PARALLEL over L (FIR, not recurrent).
// ---------------------------------------------------------------------------
__global__ __launch_bounds__(256) void conv_silu_kernel(
    const bf16_t* __restrict__ xin,  // (M,2048)
    bf16_t* __restrict__ xout,       // (M,2048)
    const float* __restrict__ cwf, const float* __restrict__ cbf,
    const float* __restrict__ cwb, const float* __restrict__ cbb)
{
    const int gid = blockIdx.x*256 + threadIdx.x;   // Bc*10*2048 threads
    const int d2 = gid & 2047;
    const int rest = gid >> 11;
    const int b = rest / 10;
    const int g = rest - b*10;
    const int l0 = g*10;
    const int half = d2 >> 10, d = d2 & 1023;
    const bf16_t* in = xin + (size_t)b*SEQ*2048 + d2;
    bf16_t* outp = xout + (size_t)b*SEQ*2048 + d2;

    if (half == 0){
        const float w0 = cwf[d*4], w1 = cwf[d*4+1], w2 = cwf[d*4+2], w3 = cwf[d*4+3];
        const float bias = cbf[d];
        float v[13];
        #pragma unroll
        for (int i = 0; i < 13; ++i){
            const int l = l0 - 3 + i;
            v[i] = (l >= 0) ? (float)in[(size_t)l*2048] : 0.f;
        }
        #pragma unroll
        for (int i = 0; i < 10; ++i){
            const float a = bias + w0*v[i] + w1*v[i+1] + w2*v[i+2] + w3*v[i+3];
            outp[(size_t)(l0+i)*2048] = (bf16_t)siluf_(a);
        }
    } else {
        const float w0 = cwb[d*2], w1 = cwb[d*2+1];
        const float bias = cbb[d];
        float v[11];
        #pragma unroll
        for (int i = 0; i < 11; ++i){
            const int l = l0 + i;
            v[i] = (l < SEQ) ? (float)in[(size_t)l*2048] : 0.f;
        }
        #pragma unroll
        for (int i = 0; i < 10; ++i){
            const float a = bias + w1*v[i] + w0*v[i+1];
            outp[(size_t)(l0+i)*2048] = (bf16_t)siluf_(a);
        }
    }
}

// ---------------------------------------------------------------------------
// Selective scan v4: r0's 1-thread-per-channel stream + cooperative LDS
// staging of x/dt/z (dword-vectorized, coalesced, each value loaded once)
// + block-uniform STRUCT dispatch via __syncthreads_and.
// Block: 128 fwd ch + 128 bwd ch of one (b, s8) slab. 10-step windows.
// ---------------------------------------------------------------------------
template<int DS>
__device__ __forceinline__ float scan_step_struct(
    float* __restrict__ h, float A0, float dtv_, float dtx, const float4* __restrict__ sxl4)
{
    const float rr = __expf(dtv_*A0);
    const float r2 = rr*rr;
    float rb = rr;
    float y0 = 0.f, y1 = 0.f, y2 = 0.f, y3 = 0.f;
    #pragma unroll
    for (int g = 0; g < DS/4; ++g){
        const float4 Bv = sxl4[g];
        const float4 Cv = sxl4[DS/4 + g];
        const float p0 = rb, p1 = rb*rr, p2 = rb*r2, p3 = p1*r2;
        h[g*4+0] = p0*h[g*4+0] + dtx*Bv.x; y0 += h[g*4+0]*Cv.x;
        h[g*4+1] = p1*h[g*4+1] + dtx*Bv.y; y1 += h[g*4+1]*Cv.y;
        h[g*4+2] = p2*h[g*4+2] + dtx*Bv.z; y2 += h[g*4+2]*Cv.z;
        h[g*4+3] = p3*h[g*4+3] + dtx*Bv.w; y3 += h[g*4+3]*Cv.w;
        rb = p3*rr;
    }
    return (y0 + y1) + (y2 + y3);
}

template<int DS>
__device__ __forceinline__ float scan_step_gen(
    float* __restrict__ h, const float* __restrict__ Av, float dtv_, float dtx,
    const float4* __restrict__ sxl4)
{
    float y0 = 0.f, y1 = 0.f, y2 = 0.f, y3 = 0.f;
    #pragma unroll
    for (int g = 0; g < DS/4; ++g){
        const float4 Bv = sxl4[g];
        const float4 Cv = sxl4[DS/4 + g];
        h[g*4+0] = __expf(dtv_*Av[g*4+0])*h[g*4+0] + dtx*Bv.x; y0 += h[g*4+0]*Cv.x;
        h[g*4+1] = __expf(dtv_*Av[g*4+1])*h[g*4+1] + dtx*Bv.y; y1 += h[g*4+1]*Cv.y;
        h[g*4+2] = __expf(dtv_*Av[g*4+2])*h[g*4+2] + dtx*Bv.z; y2 += h[g*4+2]*Cv.z;
        h[g*4+3] = __expf(dtv_*Av[g*4+3])*h[g*4+3] + dtx*Bv.w; y3 += h[g*4+3]*Cv.w;
    }
    return (y0 + y1) + (y2 + y3);
}

__global__ __launch_bounds__(256) void scan_kernel(
    bf16_t* __restrict__ xc,         // conv-x in / y out (M,2048)
    const bf16_t* __restrict__ dtv,  // dt (M,2048)
    const bf16_t* __restrict__ z,    // (M,2048)
    const float* __restrict__ xdb,   // (b,SEQ,128)
    const float* __restrict__ Alogf, const float* __restrict__ Dpf,
    const float* __restrict__ Alogb, const float* __restrict__ Dpb)
{
    const int b = blockIdx.x >> 3, s8 = blockIdx.x & 7;
    const int t = threadIdx.x;
    __shared__ float sxF[SEQ*32];          // fwd B/C slab 12.8 KB
    __shared__ float sxB[SEQ*16];          // bwd B/C slab 6.4 KB
    __shared__ uint32_t stg[3][1280];      // x/dt/z windows: [dir*640 + row*64 + col]

    // ---- B/C slabs ----
    const float4* src = (const float4*)(xdb + (size_t)b*SEQ*128);
    {
        float4* dstF = (float4*)sxF;
        for (int i = t; i < SEQ*8; i += 256){
            int row = i >> 3, c = i & 7;
            dstF[row*8 + c] = src[row*32 + 8 + c];    // fwd B/C: floats 32..63
        }
        float4* dstB = (float4*)sxB;
        for (int i = t; i < SEQ*4; i += 256){
            int row = i >> 2, c = i & 3;
            dstB[row*4 + c] = src[row*32 + 24 + c];   // bwd B/C: floats 96..111
        }
    }

    const bool fwd = (t < 128);
    const int chl = fwd ? t : (t - 128);
    const int d = s8*128 + chl;

    // ---- A values + per-thread struct check ----
    float Av[16];
    bool structp = true;
    if (fwd){
        #pragma unroll
        for (int j = 0; j < 16; ++j) Av[j] = -__expf(Alogf[d*16 + j]);
        #pragma unroll
        for (int j = 1; j < 16; ++j)
            structp = structp && (fabsf(Av[j] - (float)(j+1)*Av[0]) <= 1e-4f*(float)(j+1));
    } else {
        #pragma unroll
        for (int j = 0; j < 8; ++j) Av[j] = -__expf(Alogb[d*8 + j]);
        #pragma unroll
        for (int j = 1; j < 8; ++j)
            structp = structp && (fabsf(Av[j] - (float)(j+1)*Av[0]) <= 1e-4f*(float)(j+1));
    }
    const float Dd = fwd ? Dpf[d] : Dpb[d];
    const int allstruct = __syncthreads_and((int)structp);   // also fences B/C slab

    // ---- pointers ----
    const uint32_t* xc32 = (const uint32_t*)xc + (size_t)b*SEQ*1024;
    const uint32_t* dt32 = (const uint32_t*)dtv + (size_t)b*SEQ*1024;
    const uint32_t* z32  = (const uint32_t*)z  + (size_t)b*SEQ*1024;
    const int colF = s8*64, colB = 512 + s8*64;

    bf16_t* yout = xc + (size_t)b*SEQ*2048 + (fwd ? d : (1024 + d));
    const ushort_t* sx16 = (const ushort_t*)stg[0];
    const ushort_t* st16 = (const ushort_t*)stg[1];
    const ushort_t* sz16 = (const ushort_t*)stg[2];
    const int lb16 = (fwd ? 0 : 1280) + chl;    // u16 index; +r*128 per row

    float h[16];
    #pragma unroll
    for (int j = 0; j < 16; ++j) h[j] = 0.f;
    const float A0 = Av[0];

    #define STAGE_WIN(Q)                                                        \
        _Pragma("unroll")                                                       \
        for (int k = 0; k < 5; ++k){                                            \
            const int i = t + k*256;                                            \
            const int dir = (i >= 640) ? 1 : 0;                                 \
            const int rem = i - dir*640;                                        \
            const int row = rem >> 6, col = rem & 63;                           \
            const int grow = dir ? (99 - (Q)*10 - row) : ((Q)*10 + row);        \
            const size_t goff = (size_t)grow*1024 + (dir ? colB : colF) + col;  \
            stg[0][i] = xc32[goff];                                             \
            stg[1][i] = dt32[goff];                                             \
            stg[2][i] = z32[goff];                                              \
        }

    if (allstruct){
        #pragma unroll 1
        for (int q = 0; q < 10; ++q){
            __syncthreads();
            STAGE_WIN(q)
            __syncthreads();
            #pragma unroll
            for (int r = 0; r < 10; ++r){
                const float xv   = __uint_as_float(((uint32_t)sx16[lb16 + r*128]) << 16);
                const float dtv_ = __uint_as_float(((uint32_t)st16[lb16 + r*128]) << 16);
                const float zv   = __uint_as_float(((uint32_t)sz16[lb16 + r*128]) << 16);
                const float dtx = dtv_*xv;
                float ys;
                int li;
                if (fwd){
                    li = q*10 + r;
                    ys = scan_step_struct<16>(h, A0, dtv_, dtx, (const float4*)&sxF[li*32]);
                } else {
                    li = 99 - (q*10 + r);
                    ys = scan_step_struct<8>(h, A0, dtv_, dtx, (const float4*)&sxB[li*16]);
                }
                float yv = ys + xv*Dd;
                yv *= siluf_(zv);
                yout[(size_t)li*2048] = (bf16_t)yv;
            }
        }
    } else {
        #pragma unroll 1
        for (int q = 0; q < 10; ++q){
            __syncthreads();
            STAGE_WIN(q)
            __syncthreads();
            #pragma unroll
            for (int r = 0; r < 10; ++r){
                const float xv   = __uint_as_float(((uint32_t)sx16[lb16 + r*128]) << 16);
                const float dtv_ = __uint_as_float(((uint32_t)st16[lb16 + r*128]) << 16);
                const float zv   = __uint_as_float(((uint32_t)sz16[lb16 + r*128]) << 16);
                const float dtx = dtv_*xv;
                float ys;
                int li;
                if (fwd){
                    li = q*10 + r;
                    ys = scan_step_gen<16>(h, Av, dtv_, dtx, (const float4*)&sxF[li*32]);
                } else {
                    li = 99 - (q*10 + r);
                    ys = scan_step_gen<8>(h, Av, dtv_, dtx, (const float4*)&sxB[li*16]);
                }
                float yv = ys + xv*Dd;
                yv *= siluf_(zv);
                yout[(size_t)li*2048] = (bf16_t)yv;
            }
        }
    }
    #undef STAGE_WIN
}

// ---------------------------------------------------------------------------
// Max-pool over L, split out of head for 4x block parallelism.
// ---------------------------------------------------------------------------
__global__ __launch_bounds__(256) void pool_kernel(
    const float* __restrict__ acc,   // (Bc, L, 512)
    float* __restrict__ pooled)      // (Bc, 512)
{
    const int b = blockIdx.x, y = blockIdx.y;
    const int c = y*128 + (threadIdx.x & 127);
    const int half = threadIdx.x >> 7;
    const float* base = acc + (size_t)b*SEQ*512 + c;
    float m = -3.4e38f;
    #pragma unroll 5
    for (int l = half*50; l < half*50 + 50; ++l)
        m = fmaxf(m, base[(size_t)l*512]);
    __shared__ float sm[256];
    sm[threadIdx.x] = m;
    __syncthreads();
    if (half == 0)
        pooled[(size_t)b*512 + c] = fmaxf(sm[threadIdx.x], sm[threadIdx.x + 128]);
}

// ---------------------------------------------------------------------------
// Head: LN(512), fc1(512->128)+relu, fc2(128->4) on pooled vector
// ---------------------------------------------------------------------------
__global__ __launch_bounds__(256) void head_kernel(
    const float* __restrict__ pooled,  // (Bc, 512)
    const float* __restrict__ ng, const float* __restrict__ nb,
    const float* __restrict__ w1, const float* __restrict__ b1,
    const float* __restrict__ w2, const float* __restrict__ b2,
    float* __restrict__ out)           // (Bc, 4) chunk base
{
    const int b = blockIdx.x, t = threadIdx.x;
    __shared__ float sp[512];
    __shared__ float sh2[256];
    __shared__ float sh[128];
    __shared__ float red1[4], red2[4];

    float s1 = 0.f, s2 = 0.f;
    for (int o = t; o < 512; o += 256){
        float v = pooled[(size_t)b*512 + o];
        sp[o] = v; s1 += v; s2 += v*v;
    }
    #pragma unroll
    for (int off = 32; off > 0; off >>= 1){ s1 += __shfl_xor(s1, off); s2 += __shfl_xor(s2, off); }
    const int wv = t >> 6, lane = t & 63;
    if (lane == 0){ red1[wv] = s1; red2[wv] = s2; }
    __syncthreads();
    if (t == 0){
        float a = 0.f, c = 0.f;
        for (int i = 0; i < 4; ++i){ a += red1[i]; c += red2[i]; }
        float mean = a * (1.f/512.f);
        float var = c * (1.f/512.f) - mean*mean;
        red1[0] = mean; red2[0] = rsqrtf(var + 1e-5f);
    }
    __syncthreads();
    const float mean = red1[0], rstd = red2[0];
    for (int o = t; o < 512; o += 256) sp[o] = (sp[o]-mean)*rstd*ng[o] + nb[o];
    __syncthreads();

    {
        const int o = t & 127, half = t >> 7;
        const float4* wrow = (const float4*)(w1 + (size_t)o*512 + half*256);
        const float4* sp4 = (const float4*)sp + half*64;
        float s = 0.f;
        #pragma unroll 8
        for (int j = 0; j < 64; ++j){
            float4 a = sp4[j], wq = wrow[j];
            s += a.x*wq.x + a.y*wq.y + a.z*wq.z + a.w*wq.w;
        }
        sh2[t] = s;
    }
    __syncthreads();
    if (t < 128) sh[t] = fmaxf(sh2[t] + sh2[t + 128] + b1[t], 0.f);
    __syncthreads();
    if (t < 4){
        float a = b2[t];
        for (int j = 0; j < 128; ++j) a += sh[j]*w2[t*128 + j];
        out[b*4 + t] = a;
    }
}

// ---------------------------------------------------------------------------
extern "C" void kernel_launch(void* const* d_in, const int* in_sizes, int n_in,
                              void* d_out, int out_size, void* d_ws, size_t ws_size,
                              hipStream_t stream)
{
    (void)in_sizes; (void)n_in; (void)out_size;
    const float* x        = (const float*)d_in[0];
    const float* fe_w     = (const float*)d_in[1];
    const float* fe_b     = (const float*)d_in[2];
    const float* fe_ln_g  = (const float*)d_in[3];
    const float* fe_ln_b  = (const float*)d_in[4];
    const float* emb_ln_g = (const float*)d_in[5];
    const float* emb_ln_b = (const float*)d_in[6];
    const float* conv1_w  = (const float*)d_in[7];
    const float* conv1_b  = (const float*)d_in[8];
    const float* conv2_w  = (const float*)d_in[9];
    const float* conv2_b  = (const float*)d_in[10];
    const float* mf_in_w  = (const float*)d_in[11];
    const float* mf_conv_w= (const float*)d_in[12];
    const float* mf_conv_b= (const float*)d_in[13];
    const float* mf_xproj = (const float*)d_in[14];
    const float* mf_dt_w  = (const float*)d_in[15];
    const float* mf_dt_b  = (const float*)d_in[16];
    const float* mf_Alog  = (const float*)d_in[17];
    const float* mf_D     = (const float*)d_in[18];
    const float* mf_out_w = (const float*)d_in[19];
    const float* mb_in_w  = (const float*)d_in[20];
    const float* mb_conv_w= (const float*)d_in[21];
    const float* mb_conv_b= (const float*)d_in[22];
    const float* mb_xproj = (const float*)d_in[23];
    const float* mb_dt_w  = (const float*)d_in[24];
    const float* mb_dt_b  = (const float*)d_in[25];
    const float* mb_Alog  = (const float*)d_in[26];
    const float* mb_D     = (const float*)d_in[27];
    const float* mb_out_w = (const float*)d_in[28];
    const float* norm_g   = (const float*)d_in[29];
    const float* norm_b   = (const float*)d_in[30];
    const float* fc1_w    = (const float*)d_in[31];
    const float* fc1_b    = (const float*)d_in[32];
    const float* fc2_w    = (const float*)d_in[33];
    const float* fc2_b    = (const float*)d_in[34];
    float* out = (float*)d_out;

    // ---- fixed workspace region ----
    char* p = (char*)d_ws;
    bf16_t* w_in   = (bf16_t*)p; p += (size_t)4096*512*sizeof(bf16_t);   // [mf; mb]
    bf16_t* w_out  = (bf16_t*)p; p += (size_t)512*2048*sizeof(bf16_t);   // K-concat
    bf16_t* w_xpf  = (bf16_t*)p; p += (size_t)64*1024*sizeof(bf16_t);
    bf16_t* w_xpb  = (bf16_t*)p; p += (size_t)48*1024*sizeof(bf16_t);
    bf16_t* W1p    = (bf16_t*)p; p += (size_t)128*96*sizeof(bf16_t);
    bf16_t* W2p    = (bf16_t*)p; p += (size_t)256*384*sizeof(bf16_t);
    bf16_t* comb_all = (bf16_t*)p; p += (size_t)BSZ*SEQ*512*sizeof(bf16_t);
    const size_t fixed_bytes = (size_t)(p - (char*)d_ws);

    // ---- chunk region ----
    const size_t per_b = (size_t)SEQ * (2048*2 + 2048*2 + 2048*2 + 128*4);
    const size_t budget = (ws_size > fixed_bytes) ? (ws_size - fixed_bytes) : 0;
    int Bc = BSZ;
    while (Bc > 64 && (size_t)Bc * per_b > budget) Bc >>= 1;   // Bc in {512,256,128,64}
    const int nch = BSZ / Bc;
    const int M = Bc * SEQ;

    bf16_t* F0pad = (bf16_t*)p;   // aliases chunk region (pre-loop only)
    bf16_t* F1pad = F0pad + (size_t)BSZ*102*32;
    bf16_t* xy   = (bf16_t*)p;               p += (size_t)M*2048*sizeof(bf16_t);
    bf16_t* z    = (bf16_t*)p;               p += (size_t)M*2048*sizeof(bf16_t);
    bf16_t* dtb  = (bf16_t*)p;               p += (size_t)M*2048*sizeof(bf16_t);
    float*  xdb  = (float*)p;
    // Buffer plan per chunk:
    //   gemm_in: comb -> xy(raw x), z
    //   conv:    xy -> dtb (xc = conv+silu x)      [dtb free here]
    //   gemm_x:  dtb -> xdb                        [raw x in xy now dead]
    //   dt:      xdb -> xy (dt values)
    //   scan:    reads dtb(xc), xy(dt), z, xdb; writes y in place into dtb
    //   gemm_out: dtb(y) -> accb = (float*)xy      [dt dead after scan]
    //   pool:    (float*)xy -> xdb;  head: xdb -> out
    float*  accb = (float*)xy;

    // ---- weight conversions / rearrange ----
    cvt_bf16_kernel<<<(2048*512+255)/256, 256, 0, stream>>>(mf_in_w, w_in, 2048*512);
    cvt_bf16_kernel<<<(2048*512+255)/256, 256, 0, stream>>>(mb_in_w, w_in + (size_t)2048*512, 2048*512);
    prep_outw_kernel<<<(512*2048+255)/256, 256, 0, stream>>>(mf_out_w, mb_out_w, w_out);
    cvt_bf16_kernel<<<(64*1024+255)/256,  256, 0, stream>>>(mf_xproj, w_xpf, 64*1024);
    cvt_bf16_kernel<<<(48*1024+255)/256,  256, 0, stream>>>(mb_xproj, w_xpb, 48*1024);
    prep_convw_kernel<<<(256*384+255)/256, 256, 0, stream>>>(conv1_w, conv2_w, W1p, W2p);

    // ---- front-end ----
    fe0_kernel<<<BSZ, 256, 0, stream>>>(x, fe_w, fe_b, fe_ln_g, fe_ln_b,
        emb_ln_g, emb_ln_b, comb_all, F0pad, F1pad);
    gemm_conv_kernel<<<dim3(1, 1, BSZ), 256, 0, stream>>>(
        F0pad, 32, 102*32, W1p, 96, 128, conv1_b, F1pad, 128, 102, 1, 0, SEQ);
    gemm_conv_kernel<<<dim3(1, 2, BSZ), 256, 0, stream>>>(
        F1pad, 128, 102*128, W2p, 384, 256, conv2_b, comb_all, 512, 100, 0, 256, SEQ);

    const int gm128 = M / 128;

    for (int c = 0; c < nch; ++c){
        const size_t b0 = (size_t)c * Bc;
        const bf16_t* comb = comb_all + b0*SEQ*512;

        gemm_in_kernel<<<dim3(gm128, 32), 256, 0, stream>>>(comb, 512, M, w_in, 512, xy, z);
        conv_silu_kernel<<<Bc*80, 256, 0, stream>>>(xy, dtb, mf_conv_w, mf_conv_b,
                                                    mb_conv_w, mb_conv_b);
        gemm_x_kernel<<<dim3(gm128, 2), 256, 0, stream>>>(dtb, w_xpf, w_xpb, xdb);
        dt_kernel<<<dim3(M/16, 16), 256, 0, stream>>>(xdb, mf_dt_w, mf_dt_b,
                                                      mb_dt_w, mb_dt_b, xy);
        scan_kernel<<<Bc*8, 256, 0, stream>>>(dtb, xy, z, xdb,
                                              mf_Alog, mf_D, mb_Alog, mb_D);
        gemm_out_kernel<<<dim3(gm128, 4), 256, 0, stream>>>(dtb, M, w_out, accb);
        pool_kernel<<<dim3(Bc, 4), 256, 0, stream>>>(accb, xdb);
        head_kernel<<<Bc, 256, 0, stream>>>(xdb, norm_g, norm_b, fc1_w, fc1_b,
                                            fc2_w, fc2_b, out + b0*4);
    }
}